// Round 10
// baseline (96.423 us; speedup 1.0000x reference)
//
#include <hip/hip_runtime.h>
#include <hip/hip_bf16.h>

#define TT  2048
#define NH  32
#define NKV 8
#define DD  128
#define KVB 64          // keys per LDS tile
#define THR 8.0f        // defer-max rescale threshold (T13)

typedef __attribute__((ext_vector_type(8)))  short  short8;
typedef __attribute__((ext_vector_type(4)))  float  f32x4;
typedef __attribute__((ext_vector_type(16))) float  f32x16;
typedef unsigned int u32;
typedef __attribute__((ext_vector_type(4)))  u32    u32x4;

static __device__ __forceinline__ short f2bf(float x) {
  __bf16 b = (__bf16)x;                 // RNE f32->bf16
  return __builtin_bit_cast(short, b);
}
static __device__ __forceinline__ short8 cvt8(f32x4 a, f32x4 b) {
  short8 r;
  r[0]=f2bf(a[0]); r[1]=f2bf(a[1]); r[2]=f2bf(a[2]); r[3]=f2bf(a[3]);
  r[4]=f2bf(b[0]); r[5]=f2bf(b[1]); r[6]=f2bf(b[2]); r[7]=f2bf(b[3]);
  return r;
}
static __device__ __forceinline__ u32 pk2(float lo, float hi) {
  const u32 a = (u32)(unsigned short)f2bf(lo);
  const u32 b = (u32)(unsigned short)f2bf(hi);
  return a | (b << 16);
}
static __device__ __forceinline__ void gload_lds16(const short* g, short* l) {
  __builtin_amdgcn_global_load_lds(
      (const __attribute__((address_space(1))) u32*)g,
      (__attribute__((address_space(3))) u32*)l, 16, 0, 0);
}

// ---------------- pre-pass: K -> bf16 [kvh][j][d]; V -> bf16 transposed [kvh][d][j] ----
__global__ __launch_bounds__(256) void preconv(
    const float* __restrict__ K, const float* __restrict__ V,
    short* __restrict__ Kbf, short* __restrict__ Vtbf)
{
  const int t = threadIdx.x;
  if (blockIdx.x >= 256) {
    const int b  = blockIdx.x - 256;
    const int rr = (b << 6) + (t >> 2);      // rr = j*8+kvh
    const int q  = t & 3;
    const int j = rr >> 3, kvh = rr & 7;
    const float* src = K + (size_t)rr * DD + q * 32;
    short* dst = Kbf + ((size_t)kvh * TT + j) * DD + q * 32;
#pragma unroll
    for (int i = 0; i < 4; ++i) {
      f32x4 a  = *reinterpret_cast<const f32x4*>(src + i * 8);
      f32x4 bb = *reinterpret_cast<const f32x4*>(src + i * 8 + 4);
      *reinterpret_cast<short8*>(dst + i * 8) = cvt8(a, bb);
    }
  } else {
    const int kvh = blockIdx.x >> 5, jt = blockIdx.x & 31;
    __shared__ short Vl[64][136];
    const int jl = t >> 2, q = t & 3;
    const float* src = V + ((size_t)(jt * 64 + jl) * NKV + kvh) * DD + q * 32;
#pragma unroll
    for (int i = 0; i < 4; ++i) {
      f32x4 a  = *reinterpret_cast<const f32x4*>(src + i * 8);
      f32x4 bb = *reinterpret_cast<const f32x4*>(src + i * 8 + 4);
      *reinterpret_cast<short8*>(&Vl[jl][q * 32 + i * 8]) = cvt8(a, bb);
    }
    __syncthreads();
    const int d = t >> 1, jh = t & 1;
    short8 o[4];
#pragma unroll
    for (int k = 0; k < 4; ++k)
#pragma unroll
      for (int i = 0; i < 8; ++i)
        o[k][i] = Vl[jh * 32 + k * 8 + i][d];
    short* dst = Vtbf + ((size_t)kvh * DD + d) * TT + jt * 64 + jh * 32;
#pragma unroll
    for (int k = 0; k < 4; ++k)
      *reinterpret_cast<short8*>(dst + k * 8) = o[k];
  }
}

// ---------------- main attention kernel ------------------------------------------
// Round-7 body (proven, 81.4us) with the BLOCK->STRIP MAP FIXED for balance.
// Measured fact (r7): dispatch is static round-robin -> CU c hosts blocks c and
// c+256 sequentially (1 block/CU at 160 unified regs = 2 waves/EU). Round 7's
// q32=63-(bid>>3) paired heavy-with-heavy: CU0 queue = 32+16 = 48 tiles (the
// makespan), CU248 = 18. Balanced pairing q32 = (jj<32)? 63-jj : jj-32 gives
// CU c strips (63-j, j) whose tile counts sum to ((63-j)>>1)+(j>>1)+2 = 33 for
// EVERY j (complementary parities) -> uniform 33-tile queues, makespan ~33x4.04K.
// Block = one kv-head x 32 Q-rows; 8 waves = 4 GQA heads x 2 KEY-HALVES.
// Wave (head, kh) computes QK^T and PV over keys [32kh,32kh+32) of each 64-key
// tile with an independent per-half online softmax; halves merged once at the
// epilogue via LDS. Defer-max THR=8. K/V double-buffered, staged by
// global_load_lds with 16B-chunk XOR swizzle pre-applied on the global source.
// MFMA 32x32x16 layouts: A: lane=A[row=l&31][k=8*(l>>5)+i];
// B: B[k=8*(l>>5)+i][col=l&31]; C/D: col=l&31, row=(reg&3)+8*(reg>>2)+4*(l>>5).
__global__ __launch_bounds__(512, 2) void attn_fwd(
    const float* __restrict__ Q, const short* __restrict__ Kbf,
    const short* __restrict__ Vtbf, float* __restrict__ O,
    float* __restrict__ Mo, float* __restrict__ Lo)
{
  __shared__ __align__(16) short smem[2*KVB*DD + 2*DD*KVB];  // 64KB: Kb | Vt
  __shared__ float sx[3][2][4][32];                          // m / tmax / lsum exchange

  short (*Kb)[KVB][DD] = reinterpret_cast<short(*)[KVB][DD]>(&smem[0]);
  short (*Vt)[DD][KVB] = reinterpret_cast<short(*)[DD][KVB]>(&smem[2*KVB*DD]);

  const int bid  = blockIdx.x;
  const int kvh  = bid & (NKV - 1);          // kvh == XCD id under round-robin
  const int jj   = bid >> 3;                 // 0..63
  // BALANCED pairing (see header): CU c gets strips (63-j, j) -> 33 tiles/CU
  const int q32  = (jj < 32) ? (63 - jj) : (jj - 32);
  const int wv   = threadIdx.x >> 6;         // 0..7
  const int headq= wv & 3;
  const int kh   = wv >> 2;                  // key half of the 64-key tile
  const int lane = threadIdx.x & 63;
  const int l31  = lane & 31;
  const int hiK  = lane >> 5;
  const int l7   = lane & 7;
  const int head = kvh * 4 + headq;
  const int qbase = q32 * 32;
  const int q    = qbase + l31;              // this lane's q-column

  // ---- staging offsets: wave stages K rows [8wv,8wv+8), V d-rows [16wv,16wv+16)
  const int krow0 = 8 * wv + (lane >> 4);
  const int koff0 = krow0 * DD + ((lane & 15) ^ (krow0 & 7)) * 8;
  const int krow1 = krow0 + 4;
  const int koff1 = krow1 * DD + ((lane & 15) ^ (krow1 & 7)) * 8;
  const int vrow0 = 16 * wv + (lane >> 3);
  const int voff0 = vrow0 * TT + ((lane & 7) ^ (lane >> 3)) * 8;
  const int voff1 = voff0 + 8 * TT;

  // ---- Q B-frags: lane holds Q[qbase+l31][ks*16 + 8*hiK + i], ks=0..7 ----
  short8 aq[8];
  {
    const float* qp = Q + ((size_t)q * NH + head) * DD + hiK * 8;
#pragma unroll
    for (int ks = 0; ks < 8; ++ks) {
      const float* p = qp + ks * 16;
      aq[ks] = cvt8(*reinterpret_cast<const f32x4*>(p),
                    *reinterpret_cast<const f32x4*>(p + 4));
    }
  }

  f32x16 acc[4];
#pragma unroll
  for (int i = 0; i < 4; ++i) acc[i] = (f32x16)0.0f;
  float m = -INFINITY, tmaxh = -INFINITY, lsum = 0.0f;

  const int ntiles = (q32 >> 1) + 1;   // ceil((qbase+32)/64)

  const short* kgp = Kbf + (size_t)kvh * TT * DD;
  const short* vgp = Vtbf + (size_t)kvh * DD * TT;

  // ---- prologue: DMA tile 0 into buffer 0 ----
  gload_lds16(kgp + koff0, &Kb[0][8 * wv][0]);
  gload_lds16(kgp + koff1, &Kb[0][8 * wv + 4][0]);
  gload_lds16(vgp + voff0, &Vt[0][16 * wv][0]);
  gload_lds16(vgp + voff1, &Vt[0][16 * wv + 8][0]);
  kgp += (size_t)KVB * DD;
  vgp += KVB;

  for (int jt = 0; jt < ntiles; ++jt) {
    const int j0  = jt << 6;
    const int buf = jt & 1;

    __syncthreads();   // drains own DMA (vmcnt0); prev buffer free for overwrite

    // ---- QK^T on this wave's key half: st = S^T[key=32kh+row(r,hiK)][q=l31] ----
    f32x16 st = (f32x16)0.0f;
    const short* kr = &Kb[buf][kh * 32 + l31][0];
    __builtin_amdgcn_s_setprio(1);
#pragma unroll
    for (int ks = 0; ks < 8; ++ks) {
      const int c = ((ks << 1) | hiK) ^ l7;
      short8 kb = *reinterpret_cast<const short8*>(kr + c * 8);
      st = __builtin_amdgcn_mfma_f32_32x32x16_bf16(kb, aq[ks], st, 0, 0, 0);
    }
    __builtin_amdgcn_s_setprio(0);

    // ---- DMA tile jt+1 into buf^1 (lands during softmax+PV+next barrier) ----
    if (jt + 1 < ntiles) {
      const int nb = buf ^ 1;
      gload_lds16(kgp + koff0, &Kb[nb][8 * wv][0]);
      gload_lds16(kgp + koff1, &Kb[nb][8 * wv + 4][0]);
      gload_lds16(vgp + voff0, &Vt[nb][16 * wv][0]);
      gload_lds16(vgp + voff1, &Vt[nb][16 * wv + 8][0]);
      kgp += (size_t)KVB * DD;
      vgp += KVB;
    }

    // ---- causal mask: only the last tile can cross the diagonal ----
    if (jt == ntiles - 1) {
#pragma unroll
      for (int r = 0; r < 16; ++r) {
        const int key = j0 + kh * 32 + (r & 3) + 8 * (r >> 2) + 4 * hiK;
        if (key > q) st[r] = -1.0e10f;
      }
    }

    // ---- half-tile max (lane-local + lane^32 merge) ----
    float mx = st[0];
#pragma unroll
    for (int r = 1; r < 16; ++r) mx = fmaxf(mx, st[r]);
    mx = fmaxf(mx, __shfl_xor(mx, 32, 64));
    tmaxh = fmaxf(tmaxh, mx);

    // ---- defer-max: rescale only when the running max grows by >THR ----
    if (__any(mx > m + THR)) {
      const float mn = fmaxf(m, mx);
      const float sc = __expf(m - mn);
      m = mn;
      lsum *= sc;
#pragma unroll
      for (int r = 0; r < 16; ++r) {
        const float sf = __shfl(sc, (r & 3) + 8 * (r >> 2) + 4 * hiK, 64);
        acc[0][r] *= sf; acc[1][r] *= sf; acc[2][r] *= sf; acc[3][r] *= sf;
      }
    }

    // ---- P = exp(S-m) (bounded by e^THR); pack to PV A-frags via lane^32 ----
    float e[16];
#pragma unroll
    for (int r = 0; r < 16; ++r) e[r] = __expf(st[r] - m);
    lsum += (((e[0]+e[1])+(e[2]+e[3]))+((e[4]+e[5])+(e[6]+e[7])))
          + (((e[8]+e[9])+(e[10]+e[11]))+((e[12]+e[13])+(e[14]+e[15])));

    short8 pa[2];
#pragma unroll
    for (int h2 = 0; h2 < 2; ++h2) {
      const int b = 8 * h2;
      u32 u0 = pk2(e[b+0], e[b+1]);
      u32 u1 = pk2(e[b+2], e[b+3]);
      u32 u2 = pk2(e[b+4], e[b+5]);
      u32 u3 = pk2(e[b+6], e[b+7]);
      u32 sA = hiK ? u0 : u2;
      u32 sB = hiK ? u1 : u3;
      u32 rA = __shfl_xor(sA, 32, 64);
      u32 rB = __shfl_xor(sB, 32, 64);
      u32x4 w;
      w[0] = hiK ? rA : u0;
      w[1] = hiK ? rB : u1;
      w[2] = hiK ? u2 : rA;
      w[3] = hiK ? u3 : rB;
      pa[h2] = __builtin_bit_cast(short8, w);
    }

    // ---- P @ V over this wave's 2 key-slices ----
    __builtin_amdgcn_s_setprio(1);
#pragma unroll
    for (int dg = 0; dg < 4; ++dg) {
      const short* vr = &Vt[buf][dg * 32 + l31][0];
#pragma unroll
      for (int h2 = 0; h2 < 2; ++h2) {
        const int ksv = 2 * kh + h2;
        const int c = ((ksv << 1) | hiK) ^ l7;
        short8 vb = *reinterpret_cast<const short8*>(vr + c * 8);
        acc[dg] = __builtin_amdgcn_mfma_f32_32x32x16_bf16(pa[h2], vb, acc[dg], 0, 0, 0);
      }
    }
    __builtin_amdgcn_s_setprio(0);
  }

  // ---- epilogue: merge the two key-halves ----
  const float lw = lsum + __shfl_xor(lsum, 32, 64);
  __syncthreads();                     // all PV done; K/V LDS is dead now
  if (lane < 32) {
    sx[0][kh][headq][lane] = m;
    sx[1][kh][headq][lane] = tmaxh;
    sx[2][kh][headq][lane] = lw;
  }
  __syncthreads();
  const float mo   = sx[0][kh ^ 1][headq][l31];
  const float to   = sx[1][kh ^ 1][headq][l31];
  const float lo2  = sx[2][kh ^ 1][headq][l31];
  const float tmax = fmaxf(tmaxh, to);
  const float fsA  = __expf(m - tmax);          // own-half scale to true max
  const float ltot = lw * fsA + lo2 * __expf(mo - tmax);

  float* mbuf = reinterpret_cast<float*>(&smem[0]);   // 64KB = 4 heads x 32q x 128d
  if (kh == 1) {
#pragma unroll
    for (int r = 0; r < 16; ++r) {
      const int row = (r & 3) + 8 * (r >> 2) + 4 * hiK;
      const float sfr = __shfl(fsA, row, 64);
#pragma unroll
      for (int dg = 0; dg < 4; ++dg)
        mbuf[headq * 4096 + row * 128 + dg * 32 + l31] = acc[dg][r] * sfr;
    }
  }
  __syncthreads();
  if (kh == 0) {
#pragma unroll
    for (int r = 0; r < 16; ++r) {
      const int row = (r & 3) + 8 * (r >> 2) + 4 * hiK;
      const float sfr = __shfl(fsA, row, 64);
      const size_t ob = ((size_t)(qbase + row) * NH + head) * DD + l31;
#pragma unroll
      for (int dg = 0; dg < 4; ++dg)
        O[ob + dg * 32] = acc[dg][r] * sfr + mbuf[headq * 4096 + row * 128 + dg * 32 + l31];
    }
    if (lane < 32) {
      Mo[(size_t)q * NH + head] = tmax;
      Lo[(size_t)q * NH + head] = ltot;
    }
  }
}

extern "C" void kernel_launch(void* const* d_in, const int* in_sizes, int n_in,
                              void* d_out, int out_size, void* d_ws, size_t ws_size,
                              hipStream_t stream) {
  const float* Q = (const float*)d_in[0];
  const float* K = (const float*)d_in[1];
  const float* V = (const float*)d_in[2];
  float* O  = (float*)d_out;
  float* Mo = O + (size_t)TT * NH * DD;
  float* Lo = Mo + (size_t)TT * NH;
  short* Kbf  = (short*)d_ws;                          // 4 MB
  short* Vtbf = Kbf + (size_t)NKV * TT * DD;           // 4 MB
  preconv<<<dim3(512), dim3(256), 0, stream>>>(K, V, Kbf, Vtbf);
  attn_fwd<<<dim3(64 * NKV), dim3(512), 0, stream>>>(Q, Kbf, Vtbf, O, Mo, Lo);
}

// Round 13
// 86.044 us; speedup vs baseline: 1.1206x; 1.1206x over previous
//
#include <hip/hip_runtime.h>
#include <hip/hip_bf16.h>

#define TT  2048
#define NH  32
#define NKV 8
#define DD  128
#define KVB 64          // keys per LDS tile
#define THR 8.0f        // defer-max rescale threshold (T13)

typedef __attribute__((ext_vector_type(8)))  short  short8;
typedef __attribute__((ext_vector_type(4)))  float  f32x4;
typedef __attribute__((ext_vector_type(16))) float  f32x16;
typedef unsigned int u32;
typedef __attribute__((ext_vector_type(4)))  u32    u32x4;

static __device__ __forceinline__ short f2bf(float x) {
  __bf16 b = (__bf16)x;                 // RNE f32->bf16
  return __builtin_bit_cast(short, b);
}
static __device__ __forceinline__ short8 cvt8(f32x4 a, f32x4 b) {
  short8 r;
  r[0]=f2bf(a[0]); r[1]=f2bf(a[1]); r[2]=f2bf(a[2]); r[3]=f2bf(a[3]);
  r[4]=f2bf(b[0]); r[5]=f2bf(b[1]); r[6]=f2bf(b[2]); r[7]=f2bf(b[3]);
  return r;
}
static __device__ __forceinline__ u32 pk2(float lo, float hi) {
  const u32 a = (u32)(unsigned short)f2bf(lo);
  const u32 b = (u32)(unsigned short)f2bf(hi);
  return a | (b << 16);
}
static __device__ __forceinline__ void gload_lds16(const short* g, short* l) {
  __builtin_amdgcn_global_load_lds(
      (const __attribute__((address_space(1))) u32*)g,
      (__attribute__((address_space(3))) u32*)l, 16, 0, 0);
}

// ---------------- pre-pass: K -> bf16 [kvh][j][d]; V -> bf16 transposed [kvh][d][j] ----
__global__ __launch_bounds__(256) void preconv(
    const float* __restrict__ K, const float* __restrict__ V,
    short* __restrict__ Kbf, short* __restrict__ Vtbf)
{
  const int t = threadIdx.x;
  if (blockIdx.x >= 256) {
    const int b  = blockIdx.x - 256;
    const int rr = (b << 6) + (t >> 2);      // rr = j*8+kvh
    const int q  = t & 3;
    const int j = rr >> 3, kvh = rr & 7;
    const float* src = K + (size_t)rr * DD + q * 32;
    short* dst = Kbf + ((size_t)kvh * TT + j) * DD + q * 32;
#pragma unroll
    for (int i = 0; i < 4; ++i) {
      f32x4 a  = *reinterpret_cast<const f32x4*>(src + i * 8);
      f32x4 bb = *reinterpret_cast<const f32x4*>(src + i * 8 + 4);
      *reinterpret_cast<short8*>(dst + i * 8) = cvt8(a, bb);
    }
  } else {
    const int kvh = blockIdx.x >> 5, jt = blockIdx.x & 31;
    __shared__ short Vl[64][136];
    const int jl = t >> 2, q = t & 3;
    const float* src = V + ((size_t)(jt * 64 + jl) * NKV + kvh) * DD + q * 32;
#pragma unroll
    for (int i = 0; i < 4; ++i) {
      f32x4 a  = *reinterpret_cast<const f32x4*>(src + i * 8);
      f32x4 bb = *reinterpret_cast<const f32x4*>(src + i * 8 + 4);
      *reinterpret_cast<short8*>(&Vl[jl][q * 32 + i * 8]) = cvt8(a, bb);
    }
    __syncthreads();
    const int d = t >> 1, jh = t & 1;
    short8 o[4];
#pragma unroll
    for (int k = 0; k < 4; ++k)
#pragma unroll
      for (int i = 0; i < 8; ++i)
        o[k][i] = Vl[jh * 32 + k * 8 + i][d];
    short* dst = Vtbf + ((size_t)kvh * DD + d) * TT + jt * 64 + jh * 32;
#pragma unroll
    for (int k = 0; k < 4; ++k)
      *reinterpret_cast<short8*>(dst + k * 8) = o[k];
  }
}

// ---------------- main attention kernel ------------------------------------------
// EXACTLY the round-7 kernel (proven 81.4us) with ONE change: the next-tile DMA
// is issued immediately after the barrier (before QK^T) instead of after it.
// global_load_lds uses zero VGPRs, so the r2-era "issue late to save registers"
// rationale is obsolete; earlier issue gives the loads ~400 more cycles of slack
// before the next barrier's vmcnt-drain (the dominant per-tile stall).
// Block = one kv-head x 32 Q-rows; 8 waves = 4 GQA heads x 2 KEY-HALVES.
// Wave (head, kh) computes QK^T and PV over keys [32kh,32kh+32) of each 64-key
// tile, with an INDEPENDENT per-half online softmax (own m/lsum/tmax/acc);
// halves merged once at the epilogue via LDS with exp(m_h - tmax) scaling.
// => 1 barrier/tile. Defer-max (THR=8). LPT grid order (heaviest strips first).
// K/V double-buffered, staged by global_load_lds, 16B-chunk XOR swizzle
// (phys_chunk = logical ^ (row&7)) pre-applied on the global source address.
// MFMA 32x32x16 layouts: A: lane=A[row=l&31][k=8*(l>>5)+i];
// B: B[k=8*(l>>5)+i][col=l&31]; C/D: col=l&31, row=(reg&3)+8*(reg>>2)+4*(l>>5).
__global__ __launch_bounds__(512, 2) void attn_fwd(
    const float* __restrict__ Q, const short* __restrict__ Kbf,
    const short* __restrict__ Vtbf, float* __restrict__ O,
    float* __restrict__ Mo, float* __restrict__ Lo)
{
  __shared__ __align__(16) short smem[2*KVB*DD + 2*DD*KVB];  // 64KB: Kb | Vt
  __shared__ float sx[3][2][4][32];                          // m / tmax / lsum exchange

  short (*Kb)[KVB][DD] = reinterpret_cast<short(*)[KVB][DD]>(&smem[0]);
  short (*Vt)[DD][KVB] = reinterpret_cast<short(*)[DD][KVB]>(&smem[2*KVB*DD]);

  const int bid  = blockIdx.x;
  const int kvh  = bid & (NKV - 1);          // kvh == XCD id under round-robin
  const int q32  = 63 - (bid >> 3);          // LPT: heaviest first
  const int wv   = threadIdx.x >> 6;         // 0..7
  const int headq= wv & 3;
  const int kh   = wv >> 2;                  // key half of the 64-key tile
  const int lane = threadIdx.x & 63;
  const int l31  = lane & 31;
  const int hiK  = lane >> 5;
  const int l7   = lane & 7;
  const int head = kvh * 4 + headq;
  const int qbase = q32 * 32;
  const int q    = qbase + l31;              // this lane's q-column

  // ---- staging offsets: wave stages K rows [8wv,8wv+8), V d-rows [16wv,16wv+16)
  const int krow0 = 8 * wv + (lane >> 4);
  const int koff0 = krow0 * DD + ((lane & 15) ^ (krow0 & 7)) * 8;
  const int krow1 = krow0 + 4;
  const int koff1 = krow1 * DD + ((lane & 15) ^ (krow1 & 7)) * 8;
  const int vrow0 = 16 * wv + (lane >> 3);
  const int voff0 = vrow0 * TT + ((lane & 7) ^ (lane >> 3)) * 8;
  const int voff1 = voff0 + 8 * TT;

  // ---- Q B-frags: lane holds Q[qbase+l31][ks*16 + 8*hiK + i], ks=0..7 ----
  short8 aq[8];
  {
    const float* qp = Q + ((size_t)q * NH + head) * DD + hiK * 8;
#pragma unroll
    for (int ks = 0; ks < 8; ++ks) {
      const float* p = qp + ks * 16;
      aq[ks] = cvt8(*reinterpret_cast<const f32x4*>(p),
                    *reinterpret_cast<const f32x4*>(p + 4));
    }
  }

  f32x16 acc[4];
#pragma unroll
  for (int i = 0; i < 4; ++i) acc[i] = (f32x16)0.0f;
  float m = -INFINITY, tmaxh = -INFINITY, lsum = 0.0f;

  const int ntiles = (q32 >> 1) + 1;   // ceil((qbase+32)/64)

  const short* kgp = Kbf + (size_t)kvh * TT * DD;
  const short* vgp = Vtbf + (size_t)kvh * DD * TT;

  // ---- prologue: DMA tile 0 into buffer 0 ----
  gload_lds16(kgp + koff0, &Kb[0][8 * wv][0]);
  gload_lds16(kgp + koff1, &Kb[0][8 * wv + 4][0]);
  gload_lds16(vgp + voff0, &Vt[0][16 * wv][0]);
  gload_lds16(vgp + voff1, &Vt[0][16 * wv + 8][0]);
  kgp += (size_t)KVB * DD;
  vgp += KVB;

  for (int jt = 0; jt < ntiles; ++jt) {
    const int j0  = jt << 6;
    const int buf = jt & 1;

    __syncthreads();   // drains own DMA (vmcnt0); prev buffer free for overwrite

    // ---- DMA tile jt+1 into buf^1 IMMEDIATELY (max slack before next barrier) ----
    if (jt + 1 < ntiles) {
      const int nb = buf ^ 1;
      gload_lds16(kgp + koff0, &Kb[nb][8 * wv][0]);
      gload_lds16(kgp + koff1, &Kb[nb][8 * wv + 4][0]);
      gload_lds16(vgp + voff0, &Vt[nb][16 * wv][0]);
      gload_lds16(vgp + voff1, &Vt[nb][16 * wv + 8][0]);
      kgp += (size_t)KVB * DD;
      vgp += KVB;
    }

    // ---- QK^T on this wave's key half: st = S^T[key=32kh+row(r,hiK)][q=l31] ----
    f32x16 st = (f32x16)0.0f;
    const short* kr = &Kb[buf][kh * 32 + l31][0];
    __builtin_amdgcn_s_setprio(1);
#pragma unroll
    for (int ks = 0; ks < 8; ++ks) {
      const int c = ((ks << 1) | hiK) ^ l7;
      short8 kb = *reinterpret_cast<const short8*>(kr + c * 8);
      st = __builtin_amdgcn_mfma_f32_32x32x16_bf16(kb, aq[ks], st, 0, 0, 0);
    }
    __builtin_amdgcn_s_setprio(0);

    // ---- causal mask: only the last tile can cross the diagonal ----
    if (jt == ntiles - 1) {
#pragma unroll
      for (int r = 0; r < 16; ++r) {
        const int key = j0 + kh * 32 + (r & 3) + 8 * (r >> 2) + 4 * hiK;
        if (key > q) st[r] = -1.0e10f;
      }
    }

    // ---- half-tile max (lane-local + lane^32 merge) ----
    float mx = st[0];
#pragma unroll
    for (int r = 1; r < 16; ++r) mx = fmaxf(mx, st[r]);
    mx = fmaxf(mx, __shfl_xor(mx, 32, 64));
    tmaxh = fmaxf(tmaxh, mx);

    // ---- defer-max: rescale only when the running max grows by >THR ----
    if (__any(mx > m + THR)) {
      const float mn = fmaxf(m, mx);
      const float sc = __expf(m - mn);
      m = mn;
      lsum *= sc;
#pragma unroll
      for (int r = 0; r < 16; ++r) {
        const float sf = __shfl(sc, (r & 3) + 8 * (r >> 2) + 4 * hiK, 64);
        acc[0][r] *= sf; acc[1][r] *= sf; acc[2][r] *= sf; acc[3][r] *= sf;
      }
    }

    // ---- P = exp(S-m) (bounded by e^THR); pack to PV A-frags via lane^32 ----
    float e[16];
#pragma unroll
    for (int r = 0; r < 16; ++r) e[r] = __expf(st[r] - m);
    lsum += (((e[0]+e[1])+(e[2]+e[3]))+((e[4]+e[5])+(e[6]+e[7])))
          + (((e[8]+e[9])+(e[10]+e[11]))+((e[12]+e[13])+(e[14]+e[15])));

    short8 pa[2];
#pragma unroll
    for (int h2 = 0; h2 < 2; ++h2) {
      const int b = 8 * h2;
      u32 u0 = pk2(e[b+0], e[b+1]);
      u32 u1 = pk2(e[b+2], e[b+3]);
      u32 u2 = pk2(e[b+4], e[b+5]);
      u32 u3 = pk2(e[b+6], e[b+7]);
      u32 sA = hiK ? u0 : u2;
      u32 sB = hiK ? u1 : u3;
      u32 rA = __shfl_xor(sA, 32, 64);
      u32 rB = __shfl_xor(sB, 32, 64);
      u32x4 w;
      w[0] = hiK ? rA : u0;
      w[1] = hiK ? rB : u1;
      w[2] = hiK ? u2 : rA;
      w[3] = hiK ? u3 : rB;
      pa[h2] = __builtin_bit_cast(short8, w);
    }

    // ---- P @ V over this wave's 2 key-slices ----
    __builtin_amdgcn_s_setprio(1);
#pragma unroll
    for (int dg = 0; dg < 4; ++dg) {
      const short* vr = &Vt[buf][dg * 32 + l31][0];
#pragma unroll
      for (int h2 = 0; h2 < 2; ++h2) {
        const int ksv = 2 * kh + h2;
        const int c = ((ksv << 1) | hiK) ^ l7;
        short8 vb = *reinterpret_cast<const short8*>(vr + c * 8);
        acc[dg] = __builtin_amdgcn_mfma_f32_32x32x16_bf16(pa[h2], vb, acc[dg], 0, 0, 0);
      }
    }
    __builtin_amdgcn_s_setprio(0);
  }

  // ---- epilogue: merge the two key-halves ----
  const float lw = lsum + __shfl_xor(lsum, 32, 64);
  __syncthreads();                     // all PV done; K/V LDS is dead now
  if (lane < 32) {
    sx[0][kh][headq][lane] = m;
    sx[1][kh][headq][lane] = tmaxh;
    sx[2][kh][headq][lane] = lw;
  }
  __syncthreads();
  const float mo   = sx[0][kh ^ 1][headq][l31];
  const float to   = sx[1][kh ^ 1][headq][l31];
  const float lo2  = sx[2][kh ^ 1][headq][l31];
  const float tmax = fmaxf(tmaxh, to);
  const float fsA  = __expf(m - tmax);          // own-half scale to true max
  const float ltot = lw * fsA + lo2 * __expf(mo - tmax);

  float* mbuf = reinterpret_cast<float*>(&smem[0]);   // 64KB = 4 heads x 32q x 128d
  if (kh == 1) {
#pragma unroll
    for (int r = 0; r < 16; ++r) {
      const int row = (r & 3) + 8 * (r >> 2) + 4 * hiK;
      const float sfr = __shfl(fsA, row, 64);
#pragma unroll
      for (int dg = 0; dg < 4; ++dg)
        mbuf[headq * 4096 + row * 128 + dg * 32 + l31] = acc[dg][r] * sfr;
    }
  }
  __syncthreads();
  if (kh == 0) {
#pragma unroll
    for (int r = 0; r < 16; ++r) {
      const int row = (r & 3) + 8 * (r >> 2) + 4 * hiK;
      const float sfr = __shfl(fsA, row, 64);
      const size_t ob = ((size_t)(qbase + row) * NH + head) * DD + l31;
#pragma unroll
      for (int dg = 0; dg < 4; ++dg)
        O[ob + dg * 32] = acc[dg][r] * sfr + mbuf[headq * 4096 + row * 128 + dg * 32 + l31];
    }
    if (lane < 32) {
      Mo[(size_t)q * NH + head] = tmax;
      Lo[(size_t)q * NH + head] = ltot;
    }
  }
}

extern "C" void kernel_launch(void* const* d_in, const int* in_sizes, int n_in,
                              void* d_out, int out_size, void* d_ws, size_t ws_size,
                              hipStream_t stream) {
  const float* Q = (const float*)d_in[0];
  const float* K = (const float*)d_in[1];
  const float* V = (const float*)d_in[2];
  float* O  = (float*)d_out;
  float* Mo = O + (size_t)TT * NH * DD;
  float* Lo = Mo + (size_t)TT * NH;
  short* Kbf  = (short*)d_ws;                          // 4 MB
  short* Vtbf = Kbf + (size_t)NKV * TT * DD;           // 4 MB
  preconv<<<dim3(512), dim3(256), 0, stream>>>(K, V, Kbf, Vtbf);
  attn_fwd<<<dim3(64 * NKV), dim3(512), 0, stream>>>(Q, Kbf, Vtbf, O, Mo, Lo);
}

// Round 14
// 77.597 us; speedup vs baseline: 1.2426x; 1.1089x over previous
//
#include <hip/hip_runtime.h>
#include <hip/hip_bf16.h>

#define TT  2048
#define NH  32
#define NKV 8
#define DD  128
#define KVB 128         // keys per LDS tile (halves barrier count vs 64)
#define THR 8.0f        // defer-max rescale threshold (T13)

typedef __attribute__((ext_vector_type(8)))  short  short8;
typedef __attribute__((ext_vector_type(4)))  float  f32x4;
typedef __attribute__((ext_vector_type(16))) float  f32x16;
typedef unsigned int u32;
typedef __attribute__((ext_vector_type(4)))  u32    u32x4;

static __device__ __forceinline__ short f2bf(float x) {
  __bf16 b = (__bf16)x;                 // RNE f32->bf16
  return __builtin_bit_cast(short, b);
}
static __device__ __forceinline__ short8 cvt8(f32x4 a, f32x4 b) {
  short8 r;
  r[0]=f2bf(a[0]); r[1]=f2bf(a[1]); r[2]=f2bf(a[2]); r[3]=f2bf(a[3]);
  r[4]=f2bf(b[0]); r[5]=f2bf(b[1]); r[6]=f2bf(b[2]); r[7]=f2bf(b[3]);
  return r;
}
static __device__ __forceinline__ u32 pk2(float lo, float hi) {
  const u32 a = (u32)(unsigned short)f2bf(lo);
  const u32 b = (u32)(unsigned short)f2bf(hi);
  return a | (b << 16);
}
static __device__ __forceinline__ void gload_lds16(const short* g, short* l) {
  __builtin_amdgcn_global_load_lds(
      (const __attribute__((address_space(1))) u32*)g,
      (__attribute__((address_space(3))) u32*)l, 16, 0, 0);
}

// ---------------- pre-pass: K -> bf16 [kvh][j][d]; V -> bf16 transposed [kvh][d][j] ----
__global__ __launch_bounds__(256) void preconv(
    const float* __restrict__ K, const float* __restrict__ V,
    short* __restrict__ Kbf, short* __restrict__ Vtbf)
{
  const int t = threadIdx.x;
  if (blockIdx.x >= 256) {
    const int b  = blockIdx.x - 256;
    const int rr = (b << 6) + (t >> 2);      // rr = j*8+kvh
    const int q  = t & 3;
    const int j = rr >> 3, kvh = rr & 7;
    const float* src = K + (size_t)rr * DD + q * 32;
    short* dst = Kbf + ((size_t)kvh * TT + j) * DD + q * 32;
#pragma unroll
    for (int i = 0; i < 4; ++i) {
      f32x4 a  = *reinterpret_cast<const f32x4*>(src + i * 8);
      f32x4 bb = *reinterpret_cast<const f32x4*>(src + i * 8 + 4);
      *reinterpret_cast<short8*>(dst + i * 8) = cvt8(a, bb);
    }
  } else {
    const int kvh = blockIdx.x >> 5, jt = blockIdx.x & 31;
    __shared__ short Vl[64][136];
    const int jl = t >> 2, q = t & 3;
    const float* src = V + ((size_t)(jt * 64 + jl) * NKV + kvh) * DD + q * 32;
#pragma unroll
    for (int i = 0; i < 4; ++i) {
      f32x4 a  = *reinterpret_cast<const f32x4*>(src + i * 8);
      f32x4 bb = *reinterpret_cast<const f32x4*>(src + i * 8 + 4);
      *reinterpret_cast<short8*>(&Vl[jl][q * 32 + i * 8]) = cvt8(a, bb);
    }
    __syncthreads();
    const int d = t >> 1, jh = t & 1;
    short8 o[4];
#pragma unroll
    for (int k = 0; k < 4; ++k)
#pragma unroll
      for (int i = 0; i < 8; ++i)
        o[k][i] = Vl[jh * 32 + k * 8 + i][d];
    short* dst = Vtbf + ((size_t)kvh * DD + d) * TT + jt * 64 + jh * 32;
#pragma unroll
    for (int k = 0; k < 4; ++k)
      *reinterpret_cast<short8*>(dst + k * 8) = o[k];
  }
}

// ---------------- main attention kernel ------------------------------------------
// r7 shell (proven 81.4us: 8 waves = 4 heads x 2 key-halves, defer-max, DMA issued
// AFTER QK^T [r13 proved before-QK^T is worse], sx/mbuf epilogue) with KVB=128:
// per-strip barrier/vmcnt-drain count HALVES (the ~3.3K cyc/tile serialization S
// is paid per tile; compute W per key). Per-wave body = the r6-proven 64-key code
// (st[2] QK chains, pa[4], 16 PV MFMA) offset by the wave's key-half kh*64.
// LDS 128KB+3KB -> 1 block/CU (r7 was effectively 1 block/CU anyway: 16 waves x
// ~164 regs exceeds the VGPR file, so nothing is lost). Regs ~172 <= 256 cap.
// Only the last tile can cross the diagonal: no multiple of 128 lies strictly
// inside (qbase, qbase+32), so tile nt-2 ends at a key <= qbase.
// 16B-chunk XOR swizzle: 256B rows = 16 chunks, phys = logical ^ (row&7),
// pre-applied on the global source address (LDS dest linear), applied on reads.
// MFMA 32x32x16 layouts: A: lane=A[row=l&31][k=8*(l>>5)+i];
// B: B[k=8*(l>>5)+i][col=l&31]; C/D: col=l&31, row=(reg&3)+8*(reg>>2)+4*(l>>5).
__global__ __launch_bounds__(512, 2) void attn_fwd(
    const float* __restrict__ Q, const short* __restrict__ Kbf,
    const short* __restrict__ Vtbf, float* __restrict__ O,
    float* __restrict__ Mo, float* __restrict__ Lo)
{
  __shared__ __align__(16) short smem[2*KVB*DD + 2*DD*KVB];  // 128KB: Kb | Vt
  __shared__ float sx[3][2][4][32];                          // m / tmax / lsum exchange

  short (*Kb)[KVB][DD] = reinterpret_cast<short(*)[KVB][DD]>(&smem[0]);
  short (*Vt)[DD][KVB] = reinterpret_cast<short(*)[DD][KVB]>(&smem[2*KVB*DD]);

  const int bid  = blockIdx.x;
  const int kvh  = bid & (NKV - 1);          // kvh == XCD id under round-robin
  const int q32  = 63 - (bid >> 3);          // heaviest strips first (greedy backfill)
  const int wv   = threadIdx.x >> 6;         // 0..7
  const int headq= wv & 3;
  const int kh   = wv >> 2;                  // key half: keys [64kh, 64kh+64) per tile
  const int lane = threadIdx.x & 63;
  const int l31  = lane & 31;
  const int hiK  = lane >> 5;
  const int l7   = lane & 7;
  const int head = kvh * 4 + headq;
  const int qbase = q32 * 32;
  const int q    = qbase + l31;              // this lane's q-column

  // ---- staging offsets: wave stages K rows and V d-rows [16wv, 16wv+16) ----
  int koff[4], voff[4];
#pragma unroll
  for (int t = 0; t < 4; ++t) {
    const int row = 16 * wv + 4 * t + (lane >> 4);
    const int sw  = (lane & 15) ^ (4 * (t & 1) + (lane >> 4));
    koff[t] = row * DD + sw * 8;
    voff[t] = row * TT + sw * 8;
  }

  // ---- Q B-frags: lane holds Q[qbase+l31][ks*16 + 8*hiK + i], ks=0..7 ----
  short8 aq[8];
  {
    const float* qp = Q + ((size_t)q * NH + head) * DD + hiK * 8;
#pragma unroll
    for (int ks = 0; ks < 8; ++ks) {
      const float* p = qp + ks * 16;
      aq[ks] = cvt8(*reinterpret_cast<const f32x4*>(p),
                    *reinterpret_cast<const f32x4*>(p + 4));
    }
  }

  f32x16 acc[4];
#pragma unroll
  for (int i = 0; i < 4; ++i) acc[i] = (f32x16)0.0f;
  float m = -INFINITY, tmaxh = -INFINITY, lsum = 0.0f;

  const int ntiles = (q32 + 4) >> 2;   // ceil((qbase+32)/128)

  const short* kgp = Kbf + (size_t)kvh * TT * DD;
  const short* vgp = Vtbf + (size_t)kvh * DD * TT;

  // ---- prologue: DMA tile 0 into buffer 0 ----
#pragma unroll
  for (int t = 0; t < 4; ++t)
    gload_lds16(kgp + koff[t], &Kb[0][16 * wv + 4 * t][0]);
#pragma unroll
  for (int t = 0; t < 4; ++t)
    gload_lds16(vgp + voff[t], &Vt[0][16 * wv + 4 * t][0]);
  kgp += (size_t)KVB * DD;
  vgp += KVB;

  for (int jt = 0; jt < ntiles; ++jt) {
    const int j0  = jt << 7;
    const int buf = jt & 1;

    __syncthreads();   // drains own DMA (vmcnt0); prev buffer free for overwrite

    // ---- QK^T on this wave's 64-key half: st[kg] over keys kh*64+kg*32+[0,32) ----
    f32x16 st[2];
    st[0] = (f32x16)0.0f; st[1] = (f32x16)0.0f;
    __builtin_amdgcn_s_setprio(1);
#pragma unroll
    for (int kg = 0; kg < 2; ++kg) {
      const short* kr = &Kb[buf][kh * 64 + kg * 32 + l31][0];
#pragma unroll
      for (int ks = 0; ks < 8; ++ks) {
        const int c = ((ks << 1) | hiK) ^ l7;
        short8 kb = *reinterpret_cast<const short8*>(kr + c * 8);
        st[kg] = __builtin_amdgcn_mfma_f32_32x32x16_bf16(kb, aq[ks], st[kg], 0, 0, 0);
      }
    }
    __builtin_amdgcn_s_setprio(0);

    // ---- DMA tile jt+1 into buf^1 (r7-proven placement: after QK^T) ----
    if (jt + 1 < ntiles) {
      const int nb = buf ^ 1;
#pragma unroll
      for (int t = 0; t < 4; ++t)
        gload_lds16(kgp + koff[t], &Kb[nb][16 * wv + 4 * t][0]);
#pragma unroll
      for (int t = 0; t < 4; ++t)
        gload_lds16(vgp + voff[t], &Vt[nb][16 * wv + 4 * t][0]);
      kgp += (size_t)KVB * DD;
      vgp += KVB;
    }

    // ---- causal mask: only the last tile can cross the diagonal ----
    if (jt == ntiles - 1) {
#pragma unroll
      for (int kg = 0; kg < 2; ++kg)
#pragma unroll
        for (int r = 0; r < 16; ++r) {
          const int key = j0 + kh * 64 + kg * 32 + (r & 3) + 8 * (r >> 2) + 4 * hiK;
          if (key > q) st[kg][r] = -1.0e10f;
        }
    }

    // ---- half max (lane-local over 64 keys + lane^32 merge) ----
    float mx = fmaxf(st[0][0], st[1][0]);
#pragma unroll
    for (int r = 1; r < 16; ++r) mx = fmaxf(mx, fmaxf(st[0][r], st[1][r]));
    mx = fmaxf(mx, __shfl_xor(mx, 32, 64));
    tmaxh = fmaxf(tmaxh, mx);

    // ---- defer-max: rescale only when the running max grows by >THR ----
    if (__any(mx > m + THR)) {
      const float mn = fmaxf(m, mx);
      const float sc = __expf(m - mn);
      m = mn;
      lsum *= sc;
#pragma unroll
      for (int r = 0; r < 16; ++r) {
        const float sf = __shfl(sc, (r & 3) + 8 * (r >> 2) + 4 * hiK, 64);
        acc[0][r] *= sf; acc[1][r] *= sf; acc[2][r] *= sf; acc[3][r] *= sf;
      }
    }

    // ---- P = exp(S-m); pack to PV A-frags via lane^32 exchange ----
    short8 pa[4];
#pragma unroll
    for (int kg = 0; kg < 2; ++kg) {
      float e[16];
#pragma unroll
      for (int r = 0; r < 16; ++r) e[r] = __expf(st[kg][r] - m);
      lsum += (((e[0]+e[1])+(e[2]+e[3]))+((e[4]+e[5])+(e[6]+e[7])))
            + (((e[8]+e[9])+(e[10]+e[11]))+((e[12]+e[13])+(e[14]+e[15])));
#pragma unroll
      for (int h2 = 0; h2 < 2; ++h2) {
        const int b = 8 * h2;
        u32 u0 = pk2(e[b+0], e[b+1]);
        u32 u1 = pk2(e[b+2], e[b+3]);
        u32 u2 = pk2(e[b+4], e[b+5]);
        u32 u3 = pk2(e[b+6], e[b+7]);
        u32 sA = hiK ? u0 : u2;
        u32 sB = hiK ? u1 : u3;
        u32 rA = __shfl_xor(sA, 32, 64);
        u32 rB = __shfl_xor(sB, 32, 64);
        u32x4 w4;
        w4[0] = hiK ? rA : u0;
        w4[1] = hiK ? rB : u1;
        w4[2] = hiK ? u2 : rA;
        w4[3] = hiK ? u3 : rB;
        pa[kg * 2 + h2] = __builtin_bit_cast(short8, w4);
      }
    }

    // ---- P @ V over this wave's 4 key-slices of 16 (keys kh*64 + 16pi) ----
    __builtin_amdgcn_s_setprio(1);
#pragma unroll
    for (int dg = 0; dg < 4; ++dg) {
      const short* vr = &Vt[buf][dg * 32 + l31][0];
#pragma unroll
      for (int pi = 0; pi < 4; ++pi) {
        const int c = (8 * kh + 2 * pi + hiK) ^ l7;
        short8 vb = *reinterpret_cast<const short8*>(vr + c * 8);
        acc[dg] = __builtin_amdgcn_mfma_f32_32x32x16_bf16(pa[pi], vb, acc[dg], 0, 0, 0);
      }
    }
    __builtin_amdgcn_s_setprio(0);
  }

  // ---- epilogue: merge the two key-halves (r7 verbatim) ----
  const float lw = lsum + __shfl_xor(lsum, 32, 64);
  __syncthreads();                     // all PV done; K/V LDS is dead now
  if (lane < 32) {
    sx[0][kh][headq][lane] = m;
    sx[1][kh][headq][lane] = tmaxh;
    sx[2][kh][headq][lane] = lw;
  }
  __syncthreads();
  const float mo   = sx[0][kh ^ 1][headq][l31];
  const float to   = sx[1][kh ^ 1][headq][l31];
  const float lo2  = sx[2][kh ^ 1][headq][l31];
  const float tmax = fmaxf(tmaxh, to);
  const float fsA  = __expf(m - tmax);          // own-half scale to true max
  const float ltot = lw * fsA + lo2 * __expf(mo - tmax);

  float* mbuf = reinterpret_cast<float*>(&smem[0]);   // 64KB = 4 heads x 32q x 128d
  if (kh == 1) {
#pragma unroll
    for (int r = 0; r < 16; ++r) {
      const int row = (r & 3) + 8 * (r >> 2) + 4 * hiK;
      const float sfr = __shfl(fsA, row, 64);
#pragma unroll
      for (int dg = 0; dg < 4; ++dg)
        mbuf[headq * 4096 + row * 128 + dg * 32 + l31] = acc[dg][r] * sfr;
    }
  }
  __syncthreads();
  if (kh == 0) {
#pragma unroll
    for (int r = 0; r < 16; ++r) {
      const int row = (r & 3) + 8 * (r >> 2) + 4 * hiK;
      const float sfr = __shfl(fsA, row, 64);
      const size_t ob = ((size_t)(qbase + row) * NH + head) * DD + l31;
#pragma unroll
      for (int dg = 0; dg < 4; ++dg)
        O[ob + dg * 32] = acc[dg][r] * sfr + mbuf[headq * 4096 + row * 128 + dg * 32 + l31];
    }
    if (lane < 32) {
      Mo[(size_t)q * NH + head] = tmax;
      Lo[(size_t)q * NH + head] = ltot;
    }
  }
}

extern "C" void kernel_launch(void* const* d_in, const int* in_sizes, int n_in,
                              void* d_out, int out_size, void* d_ws, size_t ws_size,
                              hipStream_t stream) {
  const float* Q = (const float*)d_in[0];
  const float* K = (const float*)d_in[1];
  const float* V = (const float*)d_in[2];
  float* O  = (float*)d_out;
  float* Mo = O + (size_t)TT * NH * DD;
  float* Lo = Mo + (size_t)TT * NH;
  short* Kbf  = (short*)d_ws;                          // 4 MB
  short* Vtbf = Kbf + (size_t)NKV * TT * DD;           // 4 MB
  preconv<<<dim3(512), dim3(256), 0, stream>>>(K, V, Kbf, Vtbf);
  attn_fwd<<<dim3(64 * NKV), dim3(512), 0, stream>>>(Q, Kbf, Vtbf, O, Mo, Lo);
}